// Round 3
// baseline (1079.409 us; speedup 1.0000x reference)
//
#include <hip/hip_runtime.h>

#define NN    200000
#define F_IN  128
#define HID   35
#define NCLS  10
#define LD1   36     // padded row stride, 144B
#define LD2   12     // padded row stride, 48B
#define NPB   256    // nodes per bucket
#define NB    782    // ceil(200000/256)
#define CAP   5120   // bucket capacity: mean 4096 + 16 sigma
#define EPT   32     // edges per thread in k_bucket

// ---------- bucket build ----------

__global__ void k_initcur(int* __restrict__ gcur) {
    int t = threadIdx.x;
    if (t < NB) gcur[t] = t * CAP;
}

// scatter edges into 256-node destination buckets; payload = row | local_col<<18
__global__ __launch_bounds__(256)
void k_bucket(const int* __restrict__ row, const int* __restrict__ col, int E,
              int* __restrict__ gcur, unsigned* __restrict__ bkt) {
    __shared__ int hist[NB];
    __shared__ int basev[NB];
    int t = threadIdx.x;
    long e0 = (long)blockIdx.x * (256 * EPT);
    for (int i = t; i < NB; i += 256) hist[i] = 0;
    __syncthreads();
    int cols[EPT];
#pragma unroll
    for (int i = 0; i < EPT; ++i) {
        long e = e0 + (long)i * 256 + t;
        if (e < E) {
            int c = col[e];
            cols[i] = c;
            atomicAdd(&hist[c >> 8], 1);
        } else cols[i] = -1;
    }
    __syncthreads();
    for (int i = t; i < NB; i += 256) {
        int h = hist[i];
        basev[i] = (h > 0) ? atomicAdd(&gcur[i], h) : 0;
        hist[i] = 0;   // reuse as local cursor
    }
    __syncthreads();
#pragma unroll
    for (int i = 0; i < EPT; ++i) {
        int c = cols[i];
        if (c >= 0) {
            long e = e0 + (long)i * 256 + t;
            int r = row[e];
            int b = c >> 8;
            int pos = basev[b] + atomicAdd(&hist[b], 1);
            bkt[pos] = (unsigned)r | ((unsigned)(c & 255) << 18);
        }
    }
}

// per-bucket degree histogram in LDS -> dinv (no global atomics)
__global__ __launch_bounds__(256)
void k_deg(const unsigned* __restrict__ bkt, const int* __restrict__ gcur,
           float* __restrict__ dinv, int n) {
    __shared__ int cnt[NPB];
    int b = blockIdx.x, t = threadIdx.x;
    cnt[t] = 0;
    __syncthreads();
    int ec = gcur[b] - b * CAP;
    const unsigned* ep = bkt + (size_t)b * CAP;
    for (int e = t; e < ec; e += 256) atomicAdd(&cnt[ep[e] >> 18], 1);
    __syncthreads();
    int i = b * NPB + t;
    if (i < n) dinv[i] = rsqrtf((float)(cnt[t] + 1));   // +1 self loop
}

// ---------- layer 1 ----------

// hs1[i][j] = dinv[i] * sum_k x[i][k] * W1[k][j]
__global__ void k_gemm1(const float* __restrict__ x, const float* __restrict__ W1,
                        const float* __restrict__ dinv, float* __restrict__ hs1, int n) {
    int i = blockIdx.x * blockDim.x + threadIdx.x;
    if (i >= n) return;
    float acc[HID];
#pragma unroll
    for (int j = 0; j < HID; ++j) acc[j] = 0.f;
    const float4* xr = (const float4*)(x + (size_t)i * F_IN);
    for (int k4 = 0; k4 < F_IN / 4; ++k4) {
        float4 xv = xr[k4];
        const float* w = W1 + (size_t)(k4 * 4) * HID;
#pragma unroll
        for (int j = 0; j < HID; ++j)
            acc[j] += xv.x * w[j] + xv.y * w[HID + j] + xv.z * w[2 * HID + j] + xv.w * w[3 * HID + j];
    }
    float d = dinv[i];
    float* o = hs1 + (size_t)i * LD1;
#pragma unroll
    for (int j = 0; j < HID; ++j) o[j] = acc[j] * d;
    o[35] = 0.f;   // keep pad clean (read back via float4 later)
}

// acc1[c] = hs1[c] + sum_{e->c} hs1[row(e)]  via per-bucket LDS accumulators
__global__ __launch_bounds__(256)
void k_agg1(const unsigned* __restrict__ bkt, const int* __restrict__ gcur,
            const float* __restrict__ hs1, float* __restrict__ acc1, int n) {
    __shared__ float lds[NPB * LD1];   // 36 KB
    int b = blockIdx.x, t = threadIdx.x;
    int base = b * NPB;
    int nv = min(NPB, n - base);
    int nw = nv * LD1;
    const float* s0 = hs1 + (size_t)base * LD1;
    for (int i = t; i < nw; i += 256) lds[i] = s0[i];   // self-loop init
    __syncthreads();
    int ec = gcur[b] - b * CAP;
    const unsigned* ep = bkt + (size_t)b * CAP;
    for (int e = t; e < ec; e += 256) {
        unsigned p = ep[e];
        int r = p & 0x3FFFF;
        int lc = p >> 18;
        const float4* s = (const float4*)(hs1 + (size_t)r * LD1);
        float4 v[9];
#pragma unroll
        for (int q = 0; q < 9; ++q) v[q] = s[q];
        const float* vf = (const float*)v;
        float* dst = lds + lc * LD1;
#pragma unroll
        for (int f = 0; f < HID; ++f) atomicAdd(dst + f, vf[f]);
    }
    __syncthreads();
    float* o = acc1 + (size_t)base * LD1;
    for (int i = t; i < nw; i += 256) o[i] = lds[i];
}

// ---------- layer 2 ----------

// h = relu(acc1*dinv + b1); hs2 = (h @ W2) * dinv
__global__ void k_layer2(const float* __restrict__ acc1, const float* __restrict__ dinv,
                         const float* __restrict__ b1, const float* __restrict__ W2,
                         float* __restrict__ hs2, int n) {
    int i = blockIdx.x * blockDim.x + threadIdx.x;
    if (i >= n) return;
    float d = dinv[i];
    const float4* a = (const float4*)(acc1 + (size_t)i * LD1);
    float4 tq[9];
#pragma unroll
    for (int q = 0; q < 9; ++q) tq[q] = a[q];
    const float* tf = (const float*)tq;
    float h[HID];
#pragma unroll
    for (int k = 0; k < HID; ++k) {
        float v = tf[k] * d + b1[k];
        h[k] = v > 0.f ? v : 0.f;
    }
    float o[NCLS];
#pragma unroll
    for (int j = 0; j < NCLS; ++j) o[j] = 0.f;
#pragma unroll
    for (int k = 0; k < HID; ++k) {
#pragma unroll
        for (int j = 0; j < NCLS; ++j) o[j] += h[k] * W2[k * NCLS + j];
    }
    float* dst = hs2 + (size_t)i * LD2;
#pragma unroll
    for (int j = 0; j < NCLS; ++j) dst[j] = o[j] * d;
    dst[10] = 0.f;
    dst[11] = 0.f;
}

__global__ __launch_bounds__(256)
void k_agg2(const unsigned* __restrict__ bkt, const int* __restrict__ gcur,
            const float* __restrict__ hs2, float* __restrict__ acc2, int n) {
    __shared__ float lds[NPB * LD2];   // 12 KB
    int b = blockIdx.x, t = threadIdx.x;
    int base = b * NPB;
    int nv = min(NPB, n - base);
    int nw = nv * LD2;
    const float* s0 = hs2 + (size_t)base * LD2;
    for (int i = t; i < nw; i += 256) lds[i] = s0[i];
    __syncthreads();
    int ec = gcur[b] - b * CAP;
    const unsigned* ep = bkt + (size_t)b * CAP;
    for (int e = t; e < ec; e += 256) {
        unsigned p = ep[e];
        int r = p & 0x3FFFF;
        int lc = p >> 18;
        const float4* s = (const float4*)(hs2 + (size_t)r * LD2);
        float4 v0 = s[0], v1 = s[1], v2 = s[2];
        float* dst = lds + lc * LD2;
        atomicAdd(dst + 0, v0.x); atomicAdd(dst + 1, v0.y);
        atomicAdd(dst + 2, v0.z); atomicAdd(dst + 3, v0.w);
        atomicAdd(dst + 4, v1.x); atomicAdd(dst + 5, v1.y);
        atomicAdd(dst + 6, v1.z); atomicAdd(dst + 7, v1.w);
        atomicAdd(dst + 8, v2.x); atomicAdd(dst + 9, v2.y);
    }
    __syncthreads();
    float* o = acc2 + (size_t)base * LD2;
    for (int i = t; i < nw; i += 256) o[i] = lds[i];
}

// out = log_softmax(acc2*dinv + b2)
__global__ void k_out(const float* __restrict__ acc2, const float* __restrict__ dinv,
                      const float* __restrict__ b2, float* __restrict__ out, int n) {
    int i = blockIdx.x * blockDim.x + threadIdx.x;
    if (i >= n) return;
    float d = dinv[i];
    const float4* a = (const float4*)(acc2 + (size_t)i * LD2);
    float4 t0 = a[0], t1 = a[1], t2 = a[2];
    float v[NCLS] = {t0.x, t0.y, t0.z, t0.w, t1.x, t1.y, t1.z, t1.w, t2.x, t2.y};
    float m = -1e30f;
#pragma unroll
    for (int j = 0; j < NCLS; ++j) {
        v[j] = v[j] * d + b2[j];
        m = fmaxf(m, v[j]);
    }
    float s = 0.f;
#pragma unroll
    for (int j = 0; j < NCLS; ++j) s += expf(v[j] - m);
    float l = logf(s);
    float* o = out + (size_t)i * NCLS;
#pragma unroll
    for (int j = 0; j < NCLS; ++j) o[j] = v[j] - m - l;
}

extern "C" void kernel_launch(void* const* d_in, const int* in_sizes, int n_in,
                              void* d_out, int out_size, void* d_ws, size_t ws_size,
                              hipStream_t stream) {
    const float* x  = (const float*)d_in[0];
    const int*   ei = (const int*)d_in[1];
    const float* W1 = (const float*)d_in[2];
    const float* b1 = (const float*)d_in[3];
    const float* W2 = (const float*)d_in[4];
    const float* b2 = (const float*)d_in[5];
    float* out = (float*)d_out;

    const int n = in_sizes[0] / F_IN;   // 200000
    const int E = in_sizes[1] / 2;      // 3200000
    const int* row = ei;
    const int* col = ei + E;

    // workspace layout (u32 words): total 74.4 MB
    unsigned* bkt  = (unsigned*)d_ws;                 // [NB*CAP] = 4,003,840
    int*      gcur = (int*)d_ws + 4003840;            // [782]
    float*    dinv = (float*)d_ws + 4004624;          // [200000], 16B-aligned
    float*    hs1  = (float*)d_ws + 4204624;          // [7,200,000]
    float*    acc1 = (float*)d_ws + 11404624;         // [7,200,000]
    float*    hs2  = hs1;                             // alias: hs1 dead after agg1
    float*    acc2 = hs1 + 2400000;                   // alias, disjoint from hs2

    const int B = 256;
    const int nbk = (E + B * EPT - 1) / (B * EPT);    // 391

    k_initcur<<<1, 1024, 0, stream>>>(gcur);
    k_bucket<<<nbk, B, 0, stream>>>(row, col, E, gcur, bkt);
    k_deg<<<NB, B, 0, stream>>>(bkt, gcur, dinv, n);

    k_gemm1<<<(n + B - 1) / B, B, 0, stream>>>(x, W1, dinv, hs1, n);
    k_agg1<<<NB, B, 0, stream>>>(bkt, gcur, hs1, acc1, n);
    k_layer2<<<(n + B - 1) / B, B, 0, stream>>>(acc1, dinv, b1, W2, hs2, n);
    k_agg2<<<NB, B, 0, stream>>>(bkt, gcur, hs2, acc2, n);
    k_out<<<(n + B - 1) / B, B, 0, stream>>>(acc2, dinv, b2, out, n);
}

// Round 4
// 380.690 us; speedup vs baseline: 2.8354x; 2.8354x over previous
//
#include <hip/hip_runtime.h>

#define NN    200000
#define F_IN  128
#define HID   35
#define NCLS  10
#define LD1   36     // padded row stride, 144B
#define LD2   12     // padded row stride, 48B
#define NPB   256    // nodes per bucket
#define NB    782    // ceil(200000/256)
#define CAP   5120   // bucket capacity: mean 4096 + 16 sigma
#define EPT   32     // edges per thread in k_bucket

// ---------- bucket build ----------

__global__ void k_initcur(int* __restrict__ gcur) {
    int t = threadIdx.x;
    if (t < NB) gcur[t] = t * CAP;
}

// scatter edges into 256-node destination buckets; payload = row | local_col<<18
__global__ __launch_bounds__(256)
void k_bucket(const int* __restrict__ row, const int* __restrict__ col, int E,
              int* __restrict__ gcur, unsigned* __restrict__ bkt) {
    __shared__ int hist[NB];
    __shared__ int basev[NB];
    int t = threadIdx.x;
    long e0 = (long)blockIdx.x * (256 * EPT);
    for (int i = t; i < NB; i += 256) hist[i] = 0;
    __syncthreads();
    int cols[EPT];
#pragma unroll
    for (int i = 0; i < EPT; ++i) {
        long e = e0 + (long)i * 256 + t;
        if (e < E) {
            int c = col[e];
            cols[i] = c;
            atomicAdd(&hist[c >> 8], 1);
        } else cols[i] = -1;
    }
    __syncthreads();
    for (int i = t; i < NB; i += 256) {
        int h = hist[i];
        basev[i] = (h > 0) ? atomicAdd(&gcur[i], h) : 0;
        hist[i] = 0;   // reuse as local cursor
    }
    __syncthreads();
#pragma unroll
    for (int i = 0; i < EPT; ++i) {
        int c = cols[i];
        if (c >= 0) {
            long e = e0 + (long)i * 256 + t;
            int r = row[e];
            int b = c >> 8;
            int pos = basev[b] + atomicAdd(&hist[b], 1);
            if (pos < NB * CAP) bkt[pos] = (unsigned)r | ((unsigned)(c & 255) << 18);
        }
    }
}

// per-bucket LDS counting sort: bucket edges -> node order (in place),
// emits per-node [obeg,oend) ranges and dinv. No global atomics.
__global__ __launch_bounds__(256)
void k_sort(unsigned* __restrict__ bkt, const int* __restrict__ gcur,
            int* __restrict__ obeg, int* __restrict__ oend,
            float* __restrict__ dinv, int n) {
    __shared__ unsigned est[CAP];    // 20 KB edge staging
    __shared__ int hist[NPB];
    __shared__ int cur[NPB];
    __shared__ int sc[NPB];
    int b = blockIdx.x, t = threadIdx.x;
    int ec = gcur[b] - b * CAP;
    if (ec > CAP) ec = CAP;
    unsigned* ep = bkt + (size_t)b * CAP;
    hist[t] = 0;
    __syncthreads();
    for (int e = t; e < ec; e += 256) {
        unsigned p = ep[e];
        est[e] = p;
        atomicAdd(&hist[p >> 18], 1);
    }
    __syncthreads();
    // exclusive scan of hist (Hillis-Steele over 256)
    sc[t] = hist[t];
    __syncthreads();
    for (int d = 1; d < NPB; d <<= 1) {
        int add = (t >= d) ? sc[t - d] : 0;
        __syncthreads();
        sc[t] += add;
        __syncthreads();
    }
    int excl = sc[t] - hist[t];
    cur[t] = excl;
    int i = b * NPB + t;
    if (i < n) {
        obeg[i] = b * CAP + excl;
        oend[i] = b * CAP + excl + hist[t];
        dinv[i] = rsqrtf((float)(hist[t] + 1));   // +1 self loop
    }
    __syncthreads();
    for (int e = t; e < ec; e += 256) {
        unsigned p = est[e];
        int lc = p >> 18;
        int pos = atomicAdd(&cur[lc], 1);
        ep[pos] = p & 0x3FFFF;                    // store row only, node order
    }
}

// ---------- layer 1 ----------

// hs1[i][j] = dinv[i] * sum_k x[i][k] * W1[k][j]
__global__ void k_gemm1(const float* __restrict__ x, const float* __restrict__ W1,
                        const float* __restrict__ dinv, float* __restrict__ hs1, int n) {
    int i = blockIdx.x * blockDim.x + threadIdx.x;
    if (i >= n) return;
    float acc[HID];
#pragma unroll
    for (int j = 0; j < HID; ++j) acc[j] = 0.f;
    const float4* xr = (const float4*)(x + (size_t)i * F_IN);
    for (int k4 = 0; k4 < F_IN / 4; ++k4) {
        float4 xv = xr[k4];
        const float* w = W1 + (size_t)(k4 * 4) * HID;
#pragma unroll
        for (int j = 0; j < HID; ++j)
            acc[j] += xv.x * w[j] + xv.y * w[HID + j] + xv.z * w[2 * HID + j] + xv.w * w[3 * HID + j];
    }
    float d = dinv[i];
    float* o = hs1 + (size_t)i * LD1;
#pragma unroll
    for (int j = 0; j < HID; ++j) o[j] = acc[j] * d;
    o[35] = 0.f;   // keep pad clean
}

// acc1[i] = hs1[i] + sum_{e: col=i} hs1[srow[e]]  (wave per node, lane = feature, unroll 4)
__global__ void k_agg1(const int* __restrict__ obeg, const int* __restrict__ oend,
                       const unsigned* __restrict__ srow, const float* __restrict__ hs1,
                       float* __restrict__ acc1, int n) {
    int wid = (blockIdx.x * blockDim.x + threadIdx.x) >> 6;
    int lane = threadIdx.x & 63;
    if (wid >= n) return;
    int beg = obeg[wid], end = oend[wid];
    bool act = lane < LD1;
    float acc = 0.f;
    if (act) acc = hs1[(size_t)wid * LD1 + lane];        // self loop (pad lane 35 reads 0)
    int j = beg;
    for (; j + 3 < end; j += 4) {
        int r0 = srow[j], r1 = srow[j + 1], r2 = srow[j + 2], r3 = srow[j + 3];
        float a0 = 0.f, a1 = 0.f, a2 = 0.f, a3 = 0.f;
        if (act) {
            a0 = hs1[(size_t)r0 * LD1 + lane];
            a1 = hs1[(size_t)r1 * LD1 + lane];
            a2 = hs1[(size_t)r2 * LD1 + lane];
            a3 = hs1[(size_t)r3 * LD1 + lane];
        }
        acc += (a0 + a1) + (a2 + a3);
    }
    for (; j < end; ++j) {
        int r = srow[j];
        if (act) acc += hs1[(size_t)r * LD1 + lane];
    }
    if (act) acc1[(size_t)wid * LD1 + lane] = acc;
}

// ---------- layer 2 ----------

// h = relu(acc1*dinv + b1); hs2 = (h @ W2) * dinv
__global__ void k_layer2(const float* __restrict__ acc1, const float* __restrict__ dinv,
                         const float* __restrict__ b1, const float* __restrict__ W2,
                         float* __restrict__ hs2, int n) {
    int i = blockIdx.x * blockDim.x + threadIdx.x;
    if (i >= n) return;
    float d = dinv[i];
    const float4* a = (const float4*)(acc1 + (size_t)i * LD1);
    float4 tq[9];
#pragma unroll
    for (int q = 0; q < 9; ++q) tq[q] = a[q];
    const float* tf = (const float*)tq;
    float h[HID];
#pragma unroll
    for (int k = 0; k < HID; ++k) {
        float v = tf[k] * d + b1[k];
        h[k] = v > 0.f ? v : 0.f;
    }
    float o[NCLS];
#pragma unroll
    for (int j = 0; j < NCLS; ++j) o[j] = 0.f;
#pragma unroll
    for (int k = 0; k < HID; ++k) {
#pragma unroll
        for (int j = 0; j < NCLS; ++j) o[j] += h[k] * W2[k * NCLS + j];
    }
    float* dst = hs2 + (size_t)i * LD2;
#pragma unroll
    for (int j = 0; j < NCLS; ++j) dst[j] = o[j] * d;
    dst[10] = 0.f;
    dst[11] = 0.f;
}

// acc2[i] = hs2[i] + sum hs2[srow[e]]  (wave per node, 4 edges via 16-lane subgroups)
__global__ void k_agg2(const int* __restrict__ obeg, const int* __restrict__ oend,
                       const unsigned* __restrict__ srow, const float* __restrict__ hs2,
                       float* __restrict__ acc2, int n) {
    int wid = (blockIdx.x * blockDim.x + threadIdx.x) >> 6;
    int lane = threadIdx.x & 63;
    if (wid >= n) return;
    int sub = lane >> 4;          // 0..3
    int f = lane & 15;            // feature slot, active f < 12
    bool act = f < LD2;
    int beg = obeg[wid], end = oend[wid];
    float acc = 0.f;
    if (lane < LD2) acc = hs2[(size_t)wid * LD2 + lane];   // self loop (sub 0 only)
    for (int j = beg + sub; j < end; j += 4) {
        int r = srow[j];
        if (act) acc += hs2[(size_t)r * LD2 + f];
    }
    acc += __shfl_down(acc, 32);
    acc += __shfl_down(acc, 16);
    if (lane < LD2) acc2[(size_t)wid * LD2 + lane] = acc;
}

// out = log_softmax(acc2*dinv + b2)
__global__ void k_out(const float* __restrict__ acc2, const float* __restrict__ dinv,
                      const float* __restrict__ b2, float* __restrict__ out, int n) {
    int i = blockIdx.x * blockDim.x + threadIdx.x;
    if (i >= n) return;
    float d = dinv[i];
    const float4* a = (const float4*)(acc2 + (size_t)i * LD2);
    float4 t0 = a[0], t1 = a[1], t2 = a[2];
    float v[NCLS] = {t0.x, t0.y, t0.z, t0.w, t1.x, t1.y, t1.z, t1.w, t2.x, t2.y};
    float m = -1e30f;
#pragma unroll
    for (int j = 0; j < NCLS; ++j) {
        v[j] = v[j] * d + b2[j];
        m = fmaxf(m, v[j]);
    }
    float s = 0.f;
#pragma unroll
    for (int j = 0; j < NCLS; ++j) s += expf(v[j] - m);
    float l = logf(s);
    float* o = out + (size_t)i * NCLS;
#pragma unroll
    for (int j = 0; j < NCLS; ++j) o[j] = v[j] - m - l;
}

extern "C" void kernel_launch(void* const* d_in, const int* in_sizes, int n_in,
                              void* d_out, int out_size, void* d_ws, size_t ws_size,
                              hipStream_t stream) {
    const float* x  = (const float*)d_in[0];
    const int*   ei = (const int*)d_in[1];
    const float* W1 = (const float*)d_in[2];
    const float* b1 = (const float*)d_in[3];
    const float* W2 = (const float*)d_in[4];
    const float* b2 = (const float*)d_in[5];
    float* out = (float*)d_out;

    const int n = in_sizes[0] / F_IN;   // 200000
    const int E = in_sizes[1] / 2;      // 3200000
    const int* row = ei;
    const int* col = ei + E;

    // workspace layout (u32 words): total 76.0 MB, all regions 16B-aligned
    unsigned* bkt  = (unsigned*)d_ws;                 // [NB*CAP] = 4,003,840
    int*      gcur = (int*)d_ws + 4003840;            // [1024]
    int*      obeg = (int*)d_ws + 4004864;            // [200000]
    int*      oend = (int*)d_ws + 4204864;            // [200000]
    float*    dinv = (float*)d_ws + 4404864;          // [200000]
    float*    hs1  = (float*)d_ws + 4604864;          // [7,200,000]
    float*    acc1 = (float*)d_ws + 11804864;         // [7,200,000]
    float*    hs2  = hs1;                             // alias: hs1 dead after agg1
    float*    acc2 = hs1 + 2400000;                   // alias, disjoint from hs2

    const int B = 256;
    const int nbk = (E + B * EPT - 1) / (B * EPT);    // 391

    k_initcur<<<1, 1024, 0, stream>>>(gcur);
    k_bucket<<<nbk, B, 0, stream>>>(row, col, E, gcur, bkt);
    k_sort<<<NB, B, 0, stream>>>(bkt, gcur, obeg, oend, dinv, n);

    k_gemm1<<<(n + B - 1) / B, B, 0, stream>>>(x, W1, dinv, hs1, n);
    k_agg1<<<(n * 64 + B - 1) / B, B, 0, stream>>>(obeg, oend, bkt, hs1, acc1, n);
    k_layer2<<<(n + B - 1) / B, B, 0, stream>>>(acc1, dinv, b1, W2, hs2, n);
    k_agg2<<<(n * 64 + B - 1) / B, B, 0, stream>>>(obeg, oend, bkt, hs2, acc2, n);
    k_out<<<(n + B - 1) / B, B, 0, stream>>>(acc2, dinv, b2, out, n);
}

// Round 5
// 365.455 us; speedup vs baseline: 2.9536x; 1.0417x over previous
//
#include <hip/hip_runtime.h>

#define NN    200000
#define F_IN  128
#define HID   35
#define NCLS  10
#define LD1   36     // entries per row: f32 acc rows (144B) / bf16 hs rows (72B)
#define LD2   12     // entries per row: f32 acc rows (48B) / bf16 hs rows (24B)
#define NPB   256    // nodes per bucket
#define NB    782    // ceil(200000/256)
#define CAP   5120   // bucket capacity: mean 4096 + 16 sigma
#define EPT   32     // edges per thread in k_bucket

// bf16 helpers (manual RNE; avoids header/intrinsic variance)
static __device__ inline unsigned short f2bf(float f) {
    unsigned u = __float_as_uint(f);
    u = (u + 0x7FFFu + ((u >> 16) & 1u)) >> 16;
    return (unsigned short)u;
}
static __device__ inline unsigned pk2(float a, float b) {
    return (unsigned)f2bf(a) | ((unsigned)f2bf(b) << 16);
}
static __device__ inline float bf2f(unsigned short h) {
    return __uint_as_float((unsigned)h << 16);
}

// ---------- bucket build ----------

__global__ void k_initcur(int* __restrict__ gcur) {
    int t = threadIdx.x;
    if (t < NB) gcur[t] = t * CAP;
}

// scatter edges into 256-node destination buckets; payload = row | local_col<<18
__global__ __launch_bounds__(256)
void k_bucket(const int* __restrict__ row, const int* __restrict__ col, int E,
              int* __restrict__ gcur, unsigned* __restrict__ bkt) {
    __shared__ int hist[NB];
    __shared__ int basev[NB];
    int t = threadIdx.x;
    long e0 = (long)blockIdx.x * (256 * EPT);
    for (int i = t; i < NB; i += 256) hist[i] = 0;
    __syncthreads();
    int cols[EPT];
#pragma unroll
    for (int i = 0; i < EPT; ++i) {
        long e = e0 + (long)i * 256 + t;
        if (e < E) {
            int c = col[e];
            cols[i] = c;
            atomicAdd(&hist[c >> 8], 1);
        } else cols[i] = -1;
    }
    __syncthreads();
    for (int i = t; i < NB; i += 256) {
        int h = hist[i];
        basev[i] = (h > 0) ? atomicAdd(&gcur[i], h) : 0;
        hist[i] = 0;   // reuse as local cursor
    }
    __syncthreads();
#pragma unroll
    for (int i = 0; i < EPT; ++i) {
        int c = cols[i];
        if (c >= 0) {
            long e = e0 + (long)i * 256 + t;
            int r = row[e];
            int b = c >> 8;
            int pos = basev[b] + atomicAdd(&hist[b], 1);
            if (pos < NB * CAP) bkt[pos] = (unsigned)r | ((unsigned)(c & 255) << 18);
        }
    }
}

// per-bucket LDS counting sort: bucket edges -> node order (in place),
// emits per-node [obeg,oend) ranges and dinv. No global atomics.
__global__ __launch_bounds__(256)
void k_sort(unsigned* __restrict__ bkt, const int* __restrict__ gcur,
            int* __restrict__ obeg, int* __restrict__ oend,
            float* __restrict__ dinv, int n) {
    __shared__ unsigned est[CAP];    // 20 KB edge staging
    __shared__ int hist[NPB];
    __shared__ int cur[NPB];
    __shared__ int sc[NPB];
    int b = blockIdx.x, t = threadIdx.x;
    int ec = gcur[b] - b * CAP;
    if (ec > CAP) ec = CAP;
    unsigned* ep = bkt + (size_t)b * CAP;
    hist[t] = 0;
    __syncthreads();
    for (int e = t; e < ec; e += 256) {
        unsigned p = ep[e];
        est[e] = p;
        atomicAdd(&hist[p >> 18], 1);
    }
    __syncthreads();
    sc[t] = hist[t];
    __syncthreads();
    for (int d = 1; d < NPB; d <<= 1) {
        int add = (t >= d) ? sc[t - d] : 0;
        __syncthreads();
        sc[t] += add;
        __syncthreads();
    }
    int excl = sc[t] - hist[t];
    cur[t] = excl;
    int i = b * NPB + t;
    if (i < n) {
        obeg[i] = b * CAP + excl;
        oend[i] = b * CAP + excl + hist[t];
        dinv[i] = rsqrtf((float)(hist[t] + 1));   // +1 self loop
    }
    __syncthreads();
    for (int e = t; e < ec; e += 256) {
        unsigned p = est[e];
        int lc = p >> 18;
        int pos = atomicAdd(&cur[lc], 1);
        ep[pos] = p & 0x3FFFF;                    // row only, node order
    }
}

// ---------- layer 1 ----------

// hs1b[i][j] = bf16( dinv[i] * sum_k x[i][k] * W1[k][j] )
__global__ void k_gemm1(const float* __restrict__ x, const float* __restrict__ W1,
                        const float* __restrict__ dinv, unsigned short* __restrict__ hs1b,
                        int n) {
    int i = blockIdx.x * blockDim.x + threadIdx.x;
    if (i >= n) return;
    float acc[HID];
#pragma unroll
    for (int j = 0; j < HID; ++j) acc[j] = 0.f;
    const float4* xr = (const float4*)(x + (size_t)i * F_IN);
    for (int k4 = 0; k4 < F_IN / 4; ++k4) {
        float4 xv = xr[k4];
        const float* w = W1 + (size_t)(k4 * 4) * HID;
#pragma unroll
        for (int j = 0; j < HID; ++j)
            acc[j] += xv.x * w[j] + xv.y * w[HID + j] + xv.z * w[2 * HID + j] + xv.w * w[3 * HID + j];
    }
    float d = dinv[i];
    unsigned* o32 = (unsigned*)(hs1b + (size_t)i * LD1);   // 72B rows, 4B aligned
#pragma unroll
    for (int j = 0; j < 17; ++j) o32[j] = pk2(acc[2 * j] * d, acc[2 * j + 1] * d);
    o32[17] = pk2(acc[34] * d, 0.f);
}

// acc1[i] = hs1[i] + sum_{e: col=i} hs1[srow[e]]  (wave per node, lane = feature, unroll 4)
__global__ void k_agg1(const int* __restrict__ obeg, const int* __restrict__ oend,
                       const unsigned* __restrict__ srow,
                       const unsigned short* __restrict__ hs1b,
                       float* __restrict__ acc1, int n) {
    int wid = (blockIdx.x * blockDim.x + threadIdx.x) >> 6;
    int lane = threadIdx.x & 63;
    if (wid >= n) return;
    int beg = obeg[wid], end = oend[wid];
    bool act = lane < LD1;
    float acc = 0.f;
    if (act) acc = bf2f(hs1b[(size_t)wid * LD1 + lane]);   // self loop
    int j = beg;
    for (; j + 3 < end; j += 4) {
        int r0 = srow[j], r1 = srow[j + 1], r2 = srow[j + 2], r3 = srow[j + 3];
        float a0 = 0.f, a1 = 0.f, a2 = 0.f, a3 = 0.f;
        if (act) {
            a0 = bf2f(hs1b[(size_t)r0 * LD1 + lane]);
            a1 = bf2f(hs1b[(size_t)r1 * LD1 + lane]);
            a2 = bf2f(hs1b[(size_t)r2 * LD1 + lane]);
            a3 = bf2f(hs1b[(size_t)r3 * LD1 + lane]);
        }
        acc += (a0 + a1) + (a2 + a3);
    }
    for (; j < end; ++j) {
        int r = srow[j];
        if (act) acc += bf2f(hs1b[(size_t)r * LD1 + lane]);
    }
    if (act) acc1[(size_t)wid * LD1 + lane] = acc;
}

// ---------- layer 2 ----------

// h = relu(acc1*dinv + b1); hs2b = bf16( (h @ W2) * dinv )
__global__ void k_layer2(const float* __restrict__ acc1, const float* __restrict__ dinv,
                         const float* __restrict__ b1, const float* __restrict__ W2,
                         unsigned short* __restrict__ hs2b, int n) {
    int i = blockIdx.x * blockDim.x + threadIdx.x;
    if (i >= n) return;
    float d = dinv[i];
    const float4* a = (const float4*)(acc1 + (size_t)i * LD1);
    float4 tq[9];
#pragma unroll
    for (int q = 0; q < 9; ++q) tq[q] = a[q];
    const float* tf = (const float*)tq;
    float h[HID];
#pragma unroll
    for (int k = 0; k < HID; ++k) {
        float v = tf[k] * d + b1[k];
        h[k] = v > 0.f ? v : 0.f;
    }
    float o[NCLS];
#pragma unroll
    for (int j = 0; j < NCLS; ++j) o[j] = 0.f;
#pragma unroll
    for (int k = 0; k < HID; ++k) {
#pragma unroll
        for (int j = 0; j < NCLS; ++j) o[j] += h[k] * W2[k * NCLS + j];
    }
    unsigned* dst = (unsigned*)(hs2b + (size_t)i * LD2);   // 24B rows
#pragma unroll
    for (int j = 0; j < 5; ++j) dst[j] = pk2(o[2 * j] * d, o[2 * j + 1] * d);
    dst[5] = 0u;
}

// acc2[i] = hs2[i] + sum hs2[srow[e]]  (wave per node, 4 edges via 16-lane subgroups)
__global__ void k_agg2(const int* __restrict__ obeg, const int* __restrict__ oend,
                       const unsigned* __restrict__ srow,
                       const unsigned short* __restrict__ hs2b,
                       float* __restrict__ acc2, int n) {
    int wid = (blockIdx.x * blockDim.x + threadIdx.x) >> 6;
    int lane = threadIdx.x & 63;
    if (wid >= n) return;
    int sub = lane >> 4;          // 0..3
    int f = lane & 15;            // feature slot, active f < 12
    bool act = f < LD2;
    int beg = obeg[wid], end = oend[wid];
    float acc = 0.f;
    if (lane < LD2) acc = bf2f(hs2b[(size_t)wid * LD2 + lane]);   // self loop
    for (int j = beg + sub; j < end; j += 4) {
        int r = srow[j];
        if (act) acc += bf2f(hs2b[(size_t)r * LD2 + f]);
    }
    acc += __shfl_down(acc, 32);
    acc += __shfl_down(acc, 16);
    if (lane < LD2) acc2[(size_t)wid * LD2 + lane] = acc;
}

// out = log_softmax(acc2*dinv + b2)
__global__ void k_out(const float* __restrict__ acc2, const float* __restrict__ dinv,
                      const float* __restrict__ b2, float* __restrict__ out, int n) {
    int i = blockIdx.x * blockDim.x + threadIdx.x;
    if (i >= n) return;
    float d = dinv[i];
    const float4* a = (const float4*)(acc2 + (size_t)i * LD2);
    float4 t0 = a[0], t1 = a[1], t2 = a[2];
    float v[NCLS] = {t0.x, t0.y, t0.z, t0.w, t1.x, t1.y, t1.z, t1.w, t2.x, t2.y};
    float m = -1e30f;
#pragma unroll
    for (int j = 0; j < NCLS; ++j) {
        v[j] = v[j] * d + b2[j];
        m = fmaxf(m, v[j]);
    }
    float s = 0.f;
#pragma unroll
    for (int j = 0; j < NCLS; ++j) s += expf(v[j] - m);
    float l = logf(s);
    float* o = out + (size_t)i * NCLS;
#pragma unroll
    for (int j = 0; j < NCLS; ++j) o[j] = v[j] - m - l;
}

extern "C" void kernel_launch(void* const* d_in, const int* in_sizes, int n_in,
                              void* d_out, int out_size, void* d_ws, size_t ws_size,
                              hipStream_t stream) {
    const float* x  = (const float*)d_in[0];
    const int*   ei = (const int*)d_in[1];
    const float* W1 = (const float*)d_in[2];
    const float* b1 = (const float*)d_in[3];
    const float* W2 = (const float*)d_in[4];
    const float* b2 = (const float*)d_in[5];
    float* out = (float*)d_out;

    const int n = in_sizes[0] / F_IN;   // 200000
    const int E = in_sizes[1] / 2;      // 3200000
    const int* row = ei;
    const int* col = ei + E;

    // workspace layout (u32 words): max word 15,404,864 = 61.6 MB
    unsigned*       bkt  = (unsigned*)d_ws;              // [NB*CAP] = 4,003,840
    int*            gcur = (int*)d_ws + 4003840;         // [1024]
    int*            obeg = (int*)d_ws + 4004864;         // [200000]
    int*            oend = (int*)d_ws + 4204864;         // [200000]
    float*          dinv = (float*)d_ws + 4404864;       // [200000]
    unsigned short* hs1b = (unsigned short*)((unsigned*)d_ws + 4604864);  // 7.2M bf16 (3.6M words)
    float*          acc1 = (float*)d_ws + 8204864;       // [7,200,000]
    unsigned short* hs2b = hs1b;                         // alias: hs1b dead after agg1 (1.2M words)
    float*          acc2 = (float*)d_ws + 5804864;       // alias into dead hs1b space, disjoint from hs2b

    const int B = 256;
    const int nbk = (E + B * EPT - 1) / (B * EPT);       // 391

    k_initcur<<<1, 1024, 0, stream>>>(gcur);
    k_bucket<<<nbk, B, 0, stream>>>(row, col, E, gcur, bkt);
    k_sort<<<NB, B, 0, stream>>>(bkt, gcur, obeg, oend, dinv, n);

    k_gemm1<<<(n + B - 1) / B, B, 0, stream>>>(x, W1, dinv, hs1b, n);
    k_agg1<<<(n * 64 + B - 1) / B, B, 0, stream>>>(obeg, oend, bkt, hs1b, acc1, n);
    k_layer2<<<(n + B - 1) / B, B, 0, stream>>>(acc1, dinv, b1, W2, hs2b, n);
    k_agg2<<<(n * 64 + B - 1) / B, B, 0, stream>>>(obeg, oend, bkt, hs2b, acc2, n);
    k_out<<<(n + B - 1) / B, B, 0, stream>>>(acc2, dinv, b2, out, n);
}